// Round 1
// baseline (1461.510 us; speedup 1.0000x reference)
//
#include <hip/hip_runtime.h>
#include <cmath>

#define BB 8
#define LLEN 1024
#define CC 256
#define NH 8
#define HD 32
#define IMG 32
#define EPSBN 1e-5f
#define QSCALE 0.0625f   // 256^-0.5

// ---------------- transpose [b][Ld][Cd] -> [b][Cd][Ld] ----------------
__global__ __launch_bounds__(256) void k_transpose(const float* __restrict__ src,
                                                   float* __restrict__ dst,
                                                   int Ld, int Cd) {
  __shared__ float tile[32][33];
  int b = blockIdx.z;
  int l0 = blockIdx.x << 5, c0 = blockIdx.y << 5;
  int tx = threadIdx.x & 31;
  int ty = threadIdx.x >> 5;  // 0..7
  const float* s = src + (size_t)b * Ld * Cd;
  float* d = dst + (size_t)b * Ld * Cd;
#pragma unroll
  for (int i = 0; i < 32; i += 8)
    tile[ty + i][tx] = s[(size_t)(l0 + ty + i) * Cd + (c0 + tx)];
  __syncthreads();
#pragma unroll
  for (int i = 0; i < 32; i += 8)
    d[(size_t)(c0 + ty + i) * Ld + (l0 + tx)] = tile[tx][ty + i];
}

// ---------------- conv3x3 (pad 1) on feature-major input + BN stats ----------------
// inT: [B][C][L] (L = 32x32 spatial), w: [co][ci][3][3]
// outT: [B][C][L]; ssum/ssq: per-co accumulators (pre-zeroed)
__global__ __launch_bounds__(256) void k_conv_bn(const float* __restrict__ inT,
                                                 const float* __restrict__ w,
                                                 float* __restrict__ outT,
                                                 float* __restrict__ ssum,
                                                 float* __restrict__ ssq) {
  // grid (L/256=4, C/8=32, B=8), block 256
  int tid = threadIdx.x;
  int b = blockIdx.z;
  int co0 = blockIdx.y << 3;
  int l = (blockIdx.x << 8) + tid;
  int yy = l >> 5, xx = l & 31;

  int off[9];
  bool msk[9];
#pragma unroll
  for (int tap = 0; tap < 9; ++tap) {
    int dy = tap / 3 - 1, dx = tap % 3 - 1;
    int iy = yy + dy, ix = xx + dx;
    bool v = (iy >= 0) && (iy < IMG) && (ix >= 0) && (ix < IMG);
    msk[tap] = v;
    off[tap] = v ? (iy * IMG + ix) : 0;
  }

  float acc[8];
#pragma unroll
  for (int j = 0; j < 8; ++j) acc[j] = 0.f;

  const float* inb = inT + (size_t)b * CC * LLEN;
  const float* wb = w + (size_t)co0 * CC * 9;

  for (int ci = 0; ci < CC; ++ci) {
    const float* row = inb + (size_t)ci * LLEN;
#pragma unroll
    for (int tap = 0; tap < 9; ++tap) {
      float v = msk[tap] ? row[off[tap]] : 0.f;
#pragma unroll
      for (int j = 0; j < 8; ++j)
        acc[j] = fmaf(v, wb[j * CC * 9 + ci * 9 + tap], acc[j]);
    }
  }

  size_t obase = (size_t)b * CC * LLEN + l;
  int lane = tid & 63;
  int wv = tid >> 6;
  __shared__ float sred[4][8];
  __shared__ float qred[4][8];
#pragma unroll
  for (int j = 0; j < 8; ++j) {
    outT[obase + (size_t)(co0 + j) * LLEN] = acc[j];
    float s = acc[j], q = acc[j] * acc[j];
#pragma unroll
    for (int o = 32; o > 0; o >>= 1) {
      s += __shfl_down(s, o);
      q += __shfl_down(q, o);
    }
    if (lane == 0) { sred[wv][j] = s; qred[wv][j] = q; }
  }
  __syncthreads();
  if (tid < 8) {
    float s = sred[0][tid] + sred[1][tid] + sred[2][tid] + sred[3][tid];
    float q = qred[0][tid] + qred[1][tid] + qred[2][tid] + qred[3][tid];
    atomicAdd(&ssum[co0 + tid], s);
    atomicAdd(&ssq[co0 + tid], q);
  }
}

// ---------------- fold BN into projection weights ----------------
// xhat_ci = a_ci * conv_ci + d_ci ;  proj = conv @ (W*a)^T + (d @ W^T)
__global__ __launch_bounds__(256) void k_fuse_bn(const float* __restrict__ W,
                                                 const float* __restrict__ ssum,
                                                 const float* __restrict__ ssq,
                                                 const float* __restrict__ gamma,
                                                 const float* __restrict__ beta,
                                                 float* __restrict__ Wf,
                                                 float* __restrict__ bf) {
  int co = blockIdx.x, ci = threadIdx.x;
  float mu = ssum[ci] * (1.f / 8192.f);
  float var = ssq[ci] * (1.f / 8192.f) - mu * mu;
  float a = gamma[ci] * rsqrtf(var + EPSBN);
  float dt = beta[ci] - mu * a;
  float wv = W[co * CC + ci];
  Wf[co * CC + ci] = wv * a;
  __shared__ float red[256];
  red[ci] = dt * wv;
  __syncthreads();
  for (int s = 128; s > 0; s >>= 1) {
    if (ci < s) red[ci] += red[ci + s];
    __syncthreads();
  }
  if (ci == 0) bf[co] = red[0];
}

// ---------------- projection GEMM: out[b][co][l] = sum_ci A[b][ci][l]*Wf[co][ci] + bf[co] ----------------
__global__ __launch_bounds__(256) void k_proj(const float* __restrict__ A,
                                              const float* __restrict__ Wf,
                                              const float* __restrict__ bf,
                                              float* __restrict__ out) {
  // grid (L/256=4, C/16=16, B=8), block 256; thread tile: 4 co x 4 l
  __shared__ float wsh[16][256];
  int tid = threadIdx.x;
  int b = blockIdx.z;
  int co0 = blockIdx.y << 4;
#pragma unroll
  for (int r = 0; r < 16; ++r) wsh[r][tid] = Wf[(co0 + r) * CC + tid];
  __syncthreads();

  int lg = tid & 63;
  int cg = tid >> 6;  // 0..3
  int l = (blockIdx.x << 8) + (lg << 2);
  const float* Ab = A + (size_t)b * CC * LLEN + l;

  float acc[4][4];
#pragma unroll
  for (int i = 0; i < 4; ++i) {
    float bi = bf[co0 + cg * 4 + i];
#pragma unroll
    for (int j = 0; j < 4; ++j) acc[i][j] = bi;
  }

  for (int ci = 0; ci < CC; ++ci) {
    float4 v = *(const float4*)(Ab + (size_t)ci * LLEN);
#pragma unroll
    for (int i = 0; i < 4; ++i) {
      float wv = wsh[cg * 4 + i][ci];
      acc[i][0] = fmaf(v.x, wv, acc[i][0]);
      acc[i][1] = fmaf(v.y, wv, acc[i][1]);
      acc[i][2] = fmaf(v.z, wv, acc[i][2]);
      acc[i][3] = fmaf(v.w, wv, acc[i][3]);
    }
  }
  float* ob = out + (size_t)b * CC * LLEN + l;
#pragma unroll
  for (int i = 0; i < 4; ++i) {
    float4 r;
    r.x = acc[i][0]; r.y = acc[i][1]; r.z = acc[i][2]; r.w = acc[i][3];
    *(float4*)(ob + (size_t)(co0 + cg * 4 + i) * LLEN) = r;
  }
}

// ---------------- flash-style attention (fp32) ----------------
// qp/kp/vp/op: [B][C][L], head h = channels h*32..h*32+31
__device__ __forceinline__ float4 lds_ld4(const float* buf, int row, int cb) {
  return ((const float4*)buf)[(row << 4) | (cb ^ (row & 15))];
}
__device__ __forceinline__ void lds_st4(float* buf, int row, int cb, float4 v) {
  ((float4*)buf)[(row << 4) | (cb ^ (row & 15))] = v;
}

__global__ __launch_bounds__(256) void k_attn(const float* __restrict__ qp,
                                              const float* __restrict__ kp,
                                              const float* __restrict__ vp,
                                              float* __restrict__ op) {
  // grid (L/64=16, H=8, B=8), block 256 = 16 tx (t/d) x 16 ty (l)
  __shared__ float qT[32 * 64];
  __shared__ float kT[32 * 64];
  __shared__ float vT[32 * 64];
  __shared__ float pl[64 * 68];
  __shared__ float ol[32 * 68];

  int tid = threadIdx.x;
  int tx = tid & 15, ty = tid >> 4;
  int b = blockIdx.z, h = blockIdx.y, l0 = blockIdx.x << 6;

  const float* qb = qp + ((size_t)(b * CC + h * HD)) * LLEN + l0;
  const float* kb = kp + ((size_t)(b * CC + h * HD)) * LLEN;
  const float* vb = vp + ((size_t)(b * CC + h * HD)) * LLEN;

  // stage Q (scaled), swizzled, [dd][l]
#pragma unroll
  for (int i = 0; i < 2; ++i) {
    int idx = tid + (i << 8);
    int dd = idx >> 4, cb = idx & 15;
    float4 v = ((const float4*)qb)[dd * 256 + cb];
    v.x *= QSCALE; v.y *= QSCALE; v.z *= QSCALE; v.w *= QSCALE;
    lds_st4(qT, dd, cb, v);
  }

  float m_r[4], l_r[4];
  float O[4][2];
#pragma unroll
  for (int i = 0; i < 4; ++i) {
    m_r[i] = -INFINITY; l_r[i] = 0.f;
    O[i][0] = 0.f; O[i][1] = 0.f;
  }

  for (int t0 = 0; t0 < LLEN; t0 += 64) {
    __syncthreads();  // protect kT/vT/pl from previous iteration readers
#pragma unroll
    for (int i = 0; i < 2; ++i) {
      int idx = tid + (i << 8);
      int dd = idx >> 4, cb = idx & 15;
      lds_st4(kT, dd, cb, ((const float4*)kb)[dd * 256 + (t0 >> 2) + cb]);
      lds_st4(vT, dd, cb, ((const float4*)vb)[dd * 256 + (t0 >> 2) + cb]);
    }
    __syncthreads();

    // S tile: l = l0+ty*4+i, t = t0+tx*4+j
    float sc[4][4];
#pragma unroll
    for (int i = 0; i < 4; ++i)
#pragma unroll
      for (int j = 0; j < 4; ++j) sc[i][j] = 0.f;

    for (int dd = 0; dd < 32; ++dd) {
      float4 qv = lds_ld4(qT, dd, ty);
      float4 kv = lds_ld4(kT, dd, tx);
      float qa[4] = {qv.x, qv.y, qv.z, qv.w};
      float ka[4] = {kv.x, kv.y, kv.z, kv.w};
#pragma unroll
      for (int i = 0; i < 4; ++i)
#pragma unroll
        for (int j = 0; j < 4; ++j) sc[i][j] = fmaf(qa[i], ka[j], sc[i][j]);
    }

    // online softmax update per row
#pragma unroll
    for (int i = 0; i < 4; ++i) {
      float mx = fmaxf(fmaxf(sc[i][0], sc[i][1]), fmaxf(sc[i][2], sc[i][3]));
#pragma unroll
      for (int o = 8; o > 0; o >>= 1) mx = fmaxf(mx, __shfl_xor(mx, o, 16));
      float mnew = fmaxf(m_r[i], mx);
      float alpha = __expf(m_r[i] - mnew);
      float ps = 0.f;
#pragma unroll
      for (int j = 0; j < 4; ++j) {
        sc[i][j] = __expf(sc[i][j] - mnew);
        ps += sc[i][j];
      }
      *(float4*)&pl[(ty * 4 + i) * 68 + tx * 4] =
          make_float4(sc[i][0], sc[i][1], sc[i][2], sc[i][3]);
#pragma unroll
      for (int o = 8; o > 0; o >>= 1) ps += __shfl_xor(ps, o, 16);
      l_r[i] = l_r[i] * alpha + ps;
      m_r[i] = mnew;
      O[i][0] *= alpha;
      O[i][1] *= alpha;
    }
    __syncthreads();

    // O[l][d] += P[l][t] * V[d][t] ; d = tx*2+j
    for (int ts = 0; ts < 64; ts += 4) {
      float4 v0 = lds_ld4(vT, tx * 2 + 0, ts >> 2);
      float4 v1 = lds_ld4(vT, tx * 2 + 1, ts >> 2);
#pragma unroll
      for (int i = 0; i < 4; ++i) {
        float4 p = *(const float4*)&pl[(ty * 4 + i) * 68 + ts];
        O[i][0] = fmaf(p.x, v0.x, O[i][0]);
        O[i][0] = fmaf(p.y, v0.y, O[i][0]);
        O[i][0] = fmaf(p.z, v0.z, O[i][0]);
        O[i][0] = fmaf(p.w, v0.w, O[i][0]);
        O[i][1] = fmaf(p.x, v1.x, O[i][1]);
        O[i][1] = fmaf(p.y, v1.y, O[i][1]);
        O[i][1] = fmaf(p.z, v1.z, O[i][1]);
        O[i][1] = fmaf(p.w, v1.w, O[i][1]);
      }
    }
  }

  // normalize, transpose via LDS, write [d][l] rows coalesced
#pragma unroll
  for (int i = 0; i < 4; ++i) {
    float inv = 1.0f / l_r[i];
    ol[(tx * 2 + 0) * 68 + ty * 4 + i] = O[i][0] * inv;
    ol[(tx * 2 + 1) * 68 + ty * 4 + i] = O[i][1] * inv;
  }
  __syncthreads();
  float* ob = op + ((size_t)(b * CC + h * HD)) * LLEN + l0;
#pragma unroll
  for (int i = 0; i < 2; ++i) {
    int idx = tid + (i << 8);
    int dd = idx >> 4, cb = idx & 15;
    *(float4*)(ob + (size_t)dd * LLEN + cb * 4) = *(const float4*)&ol[dd * 68 + cb * 4];
  }
}

// ---------------- output GEMM: out[b][l][co] = sum_ci A[b][ci][l]*WoT[ci][co] + bo[co] ----------------
__global__ __launch_bounds__(256) void k_out(const float* __restrict__ A,
                                             const float* __restrict__ WoT,
                                             const float* __restrict__ bo,
                                             float* __restrict__ out) {
  // grid (L/32=32, B=8), block 256
  __shared__ float Al[256 * 32];
  int tid = threadIdx.x;
  int b = blockIdx.y;
  int l0 = blockIdx.x << 5;
  const float* Ab = A + (size_t)b * CC * LLEN + l0;
#pragma unroll
  for (int i = 0; i < 8; ++i) {
    int idx = tid + (i << 8);  // 2048 float4 slots: 256 ci x 8
    int ci = idx >> 3, c4 = idx & 7;
    *(float4*)&Al[ci * 32 + c4 * 4] = *(const float4*)(Ab + (size_t)ci * LLEN + c4 * 4);
  }
  __syncthreads();

  int lane = tid & 63, wv = tid >> 6;
  int co = lane << 2;
  float4 bv = *(const float4*)&bo[co];
  float acc[8][4];
#pragma unroll
  for (int i = 0; i < 8; ++i) {
    acc[i][0] = bv.x; acc[i][1] = bv.y; acc[i][2] = bv.z; acc[i][3] = bv.w;
  }
  for (int ci = 0; ci < CC; ++ci) {
    float4 w4 = *(const float4*)&WoT[ci * CC + co];
#pragma unroll
    for (int i = 0; i < 8; ++i) {
      float a = Al[ci * 32 + wv * 8 + i];
      acc[i][0] = fmaf(a, w4.x, acc[i][0]);
      acc[i][1] = fmaf(a, w4.y, acc[i][1]);
      acc[i][2] = fmaf(a, w4.z, acc[i][2]);
      acc[i][3] = fmaf(a, w4.w, acc[i][3]);
    }
  }
  float* ob = out + ((size_t)b * LLEN + l0 + wv * 8) * CC + co;
#pragma unroll
  for (int i = 0; i < 8; ++i) {
    float4 r;
    r.x = acc[i][0]; r.y = acc[i][1]; r.z = acc[i][2]; r.w = acc[i][3];
    *(float4*)(ob + (size_t)i * CC) = r;
  }
}

extern "C" void kernel_launch(void* const* d_in, const int* in_sizes, int n_in,
                              void* d_out, int out_size, void* d_ws, size_t ws_size,
                              hipStream_t stream) {
  (void)in_sizes; (void)n_in; (void)out_size; (void)ws_size;
  const float* x  = (const float*)d_in[0];
  const float* y  = (const float*)d_in[1];
  const float* wq = (const float*)d_in[4];
  const float* gq = (const float*)d_in[5];
  const float* bq = (const float*)d_in[6];
  const float* wk = (const float*)d_in[7];
  const float* gk = (const float*)d_in[8];
  const float* bk = (const float*)d_in[9];
  const float* wv = (const float*)d_in[10];
  const float* gv = (const float*)d_in[11];
  const float* bv = (const float*)d_in[12];
  const float* Wq = (const float*)d_in[13];
  const float* Wk = (const float*)d_in[14];
  const float* Wv = (const float*)d_in[15];
  const float* Wo = (const float*)d_in[16];
  const float* bo = (const float*)d_in[17];
  float* out = (float*)d_out;

  const size_t NF = (size_t)BB * CC * LLEN;  // 2M floats
  float* ws  = (float*)d_ws;
  float* xT  = ws;             // later: q projection [B][C][L]
  float* yT  = ws + NF;        // later: k projection
  float* cq  = ws + 2 * NF;    // conv-q out; later: v projection
  float* ck  = ws + 3 * NF;    // conv-k out; later: attention out
  float* cv  = ws + 4 * NF;    // conv-v out
  float* st  = ws + 5 * NF;    // 6 x 256 stats
  float* bfq = st + 1536;
  float* bfk = bfq + 256;
  float* bfv = bfk + 256;
  float* Wfq = bfv + 256;
  float* Wfk = Wfq + 65536;
  float* Wfv = Wfk + 65536;
  float* WoT = Wfv + 65536;

  hipMemsetAsync(st, 0, 1536 * sizeof(float), stream);

  dim3 tgrid(32, 8, 8);
  k_transpose<<<tgrid, 256, 0, stream>>>(x, xT, LLEN, CC);
  k_transpose<<<tgrid, 256, 0, stream>>>(y, yT, LLEN, CC);

  dim3 cgrid(4, 32, 8);
  k_conv_bn<<<cgrid, 256, 0, stream>>>(xT, wq, cq, st + 0,    st + 256);
  k_conv_bn<<<cgrid, 256, 0, stream>>>(yT, wk, ck, st + 512,  st + 768);
  k_conv_bn<<<cgrid, 256, 0, stream>>>(yT, wv, cv, st + 1024, st + 1280);

  k_fuse_bn<<<256, 256, 0, stream>>>(Wq, st + 0,    st + 256,  gq, bq, Wfq, bfq);
  k_fuse_bn<<<256, 256, 0, stream>>>(Wk, st + 512,  st + 768,  gk, bk, Wfk, bfk);
  k_fuse_bn<<<256, 256, 0, stream>>>(Wv, st + 1024, st + 1280, gv, bv, Wfv, bfv);

  k_transpose<<<dim3(8, 8, 1), 256, 0, stream>>>(Wo, WoT, 256, 256);

  dim3 pgrid(4, 16, 8);
  k_proj<<<pgrid, 256, 0, stream>>>(cq, Wfq, bfq, xT);
  k_proj<<<pgrid, 256, 0, stream>>>(ck, Wfk, bfk, yT);
  k_proj<<<pgrid, 256, 0, stream>>>(cv, Wfv, bfv, cq);

  dim3 agrid(16, 8, 8);
  k_attn<<<agrid, 256, 0, stream>>>(xT, yT, cq, ck);

  k_out<<<dim3(32, 8), 256, 0, stream>>>(ck, WoT, bo, out);
}